// Round 1
// baseline (1050.045 us; speedup 1.0000x reference)
//
#include <hip/hip_runtime.h>
#include <hip/hip_bf16.h>

// Problem constants (PConvLinear): B=2, N=60000, K=16, C_in=64, C_add=3,
// C_mid=16 -> F = 67*16 = 1072 features into a 1072->128 linear layer.
#define NPTS   60000
#define NBLK   3750        // NPTS / TM
#define TM     16          // points per block
#define THREADS 256
#define F      1072
#define OUTF   128
#define PSTR   1096        // sP per-point stride (bf16 elems); 1096*2/4 % 32 = 4 -> banks spread
#define LWSTR  132         // sLW row stride (floats); pad 128 -> 132

typedef __attribute__((ext_vector_type(4))) short short4v;

__device__ __forceinline__ float bf2f(short s) {
    union { unsigned u; float f; } cvt;
    cvt.u = ((unsigned)(unsigned short)s) << 16;
    return cvt.f;
}

extern "C" __global__ void __launch_bounds__(THREADS)
pconv_linear_kernel(const float* __restrict__ inF,   // [B][N][64]
                    const int*   __restrict__ inds,  // [B][N][16]
                    const float* __restrict__ Wn,    // [B][N][16][16]
                    const float* __restrict__ addF,  // [B][N][16][3]
                    const float* __restrict__ LW,    // [128][1072]
                    const float* __restrict__ bias,  // [128]
                    float*       __restrict__ out)   // [B][N][128]
{
    __shared__ __hip_bfloat16 sP[TM * PSTR];   // pconv tile, bf16
    __shared__ float sLW[32 * LWSTR];          // staged LW chunk [fl][o]

    const int t   = threadIdx.x;
    const int bid = blockIdx.x;
    const int b   = bid / NBLK;
    const int n0  = (bid - b * NBLK) * TM;

    // ---------------- Phase A: pconv tile -> sP (bf16) ----------------
    // thread (p = t>>4, m = t&15) computes pconv[p][c][m] for all c.
    {
        const int p = t >> 4;
        const int m = t & 15;
        const int n = n0 + p;
        const int base_nk = (b * NPTS + n) * 16;   // row base for inds/Wn/addF

        float wreg[16];
        #pragma unroll
        for (int k = 0; k < 16; ++k)
            wreg[k] = Wn[(base_nk + k) * 16 + m];   // W[b][n][k][m]

        int rowoff[16];
        #pragma unroll
        for (int k = 0; k < 16; ++k)
            rowoff[k] = (b * NPTS + inds[base_nk + k]) * 64;

        __hip_bfloat16* dst = &sP[p * PSTR + m];

        // c = 0..63 from gathered input_features (fp32, L1-resident rows)
        for (int c4 = 0; c4 < 64; c4 += 4) {
            float4 fv[16];
            #pragma unroll
            for (int k = 0; k < 16; ++k)
                fv[k] = *(const float4*)(inF + rowoff[k] + c4);
            #pragma unroll
            for (int cc = 0; cc < 4; ++cc) {
                float s = 0.f;
                #pragma unroll
                for (int k = 0; k < 16; ++k)
                    s += ((const float*)&fv[k])[cc] * wreg[k];
                dst[(c4 + cc) * 16] = __float2bfloat16(s);
            }
        }
        // c = 64..66 from additional_features
        {
            float s0 = 0.f, s1 = 0.f, s2 = 0.f;
            #pragma unroll
            for (int k = 0; k < 16; ++k) {
                const float* ap = addF + (base_nk + k) * 3;
                const float w = wreg[k];
                s0 += ap[0] * w;
                s1 += ap[1] * w;
                s2 += ap[2] * w;
            }
            dst[64 * 16] = __float2bfloat16(s0);
            dst[65 * 16] = __float2bfloat16(s1);
            dst[66 * 16] = __float2bfloat16(s2);
        }
        // zero-pad f = 1072..1087 so phase B's last chunk reads zeros
        sP[p * PSTR + 1072 + m] = __float2bfloat16(0.f);
    }
    __syncthreads();

    // ---------------- Phase B: out[16 x 128] = sP @ LW^T + bias ----------------
    // thread (pq = t>>5, og = t&31): points {2pq, 2pq+1}, outputs og*4..og*4+3
    const int pq = t >> 5;
    const int og = t & 31;
    const int o  = og * 4;
    const int p0 = pq * 2, p1 = p0 + 1;

    float4 acc0 = make_float4(0.f, 0.f, 0.f, 0.f);
    float4 acc1 = make_float4(0.f, 0.f, 0.f, 0.f);

    const int oS   = t >> 1;   // 0..127 : output row staged by this thread
    const int half = t & 1;    // which 16-wide half of the 32-wide f-chunk

    for (int f0 = 0; f0 < F; f0 += 32) {    // 34 chunks; last is half-padded
        // stage LW[o][f0..f0+31] into sLW[fl][o]
        {
            const int fl0 = half * 16;
            const int f   = f0 + fl0;
            if (f < F) {
                const float* src = LW + oS * F + f;
                #pragma unroll
                for (int j = 0; j < 16; j += 4) {
                    float4 v = *(const float4*)(src + j);
                    sLW[(fl0 + j + 0) * LWSTR + oS] = v.x;
                    sLW[(fl0 + j + 1) * LWSTR + oS] = v.y;
                    sLW[(fl0 + j + 2) * LWSTR + oS] = v.z;
                    sLW[(fl0 + j + 3) * LWSTR + oS] = v.w;
                }
            } else {
                #pragma unroll
                for (int j = 0; j < 16; ++j)
                    sLW[(fl0 + j) * LWSTR + oS] = 0.f;
            }
        }
        __syncthreads();

        #pragma unroll
        for (int fl = 0; fl < 32; fl += 4) {
            short4v pa = *(const short4v*)(const void*)&sP[p0 * PSTR + f0 + fl];
            short4v pb = *(const short4v*)(const void*)&sP[p1 * PSTR + f0 + fl];
            #pragma unroll
            for (int i = 0; i < 4; ++i) {
                float4 lw = *(const float4*)&sLW[(fl + i) * LWSTR + o];
                const float av = bf2f(pa[i]);
                const float bv = bf2f(pb[i]);
                acc0.x += av * lw.x; acc0.y += av * lw.y;
                acc0.z += av * lw.z; acc0.w += av * lw.w;
                acc1.x += bv * lw.x; acc1.y += bv * lw.y;
                acc1.z += bv * lw.z; acc1.w += bv * lw.w;
            }
        }
        __syncthreads();
    }

    // ---------------- Epilogue: + bias, coalesced float4 stores ----------------
    {
        const float4 bz = *(const float4*)&bias[o];
        float4 r0, r1;
        r0.x = acc0.x + bz.x; r0.y = acc0.y + bz.y;
        r0.z = acc0.z + bz.z; r0.w = acc0.w + bz.w;
        r1.x = acc1.x + bz.x; r1.y = acc1.y + bz.y;
        r1.z = acc1.z + bz.z; r1.w = acc1.w + bz.w;
        float* optr0 = out + ((long)(b * NPTS + n0 + p0)) * OUTF + o;
        float* optr1 = out + ((long)(b * NPTS + n0 + p1)) * OUTF + o;
        *(float4*)optr0 = r0;
        *(float4*)optr1 = r1;
    }
}

extern "C" void kernel_launch(void* const* d_in, const int* in_sizes, int n_in,
                              void* d_out, int out_size, void* d_ws, size_t ws_size,
                              hipStream_t stream)
{
    const float* inF  = (const float*)d_in[0];  // input_features  [2][60000][64]
    const int*   inds = (const int*)  d_in[1];  // neighbor_inds   [2][60000][16]
    const float* Wn   = (const float*)d_in[2];  // weightnet       [2][60000][16][16]
    const float* addF = (const float*)d_in[3];  // additional_feat [2][60000][16][3]
    const float* LW   = (const float*)d_in[4];  // linear_weight   [128][1072]
    const float* bias = (const float*)d_in[5];  // linear_bias     [128]
    float* out = (float*)d_out;                 // [2][60000][128]

    dim3 grid(2 * NBLK);   // one block per 16 points, batches concatenated
    pconv_linear_kernel<<<grid, THREADS, 0, stream>>>(inF, inds, Wn, addF, LW, bias, out);
}

// Round 2
// 519.285 us; speedup vs baseline: 2.0221x; 2.0221x over previous
//
#include <hip/hip_runtime.h>
#include <hip/hip_bf16.h>

// PConvLinear: B=2, N=60000, K=16, C_in=64, C_add=3, C_mid=16.
// pconv[p][c][m] = sum_k feat[p][k][c] * Wn[p][k][m]   (c in 0..66)
// out[p][o]     = sum_f pconv_flat[p][f] * LW[o][f] + bias[o],  f = c*16+m, F=1072
#define NPTS  60000
#define NBLK  3750          // blocks per batch (16 points each)
#define FP    1088          // F padded to 34*32 for K-chunking
#define PSTR  1096          // sP row stride (f16): 1088 + 8 -> 548 dw % 32 = 4 (2-way, free)
#define LWH_BYTES (128 * FP * 2)

typedef _Float16 f16x8 __attribute__((ext_vector_type(8)));
typedef float    f32x4 __attribute__((ext_vector_type(4)));

// ---- pre-kernel: linear_weight fp32 [128][1072] -> f16 [128][1088] in d_ws ----
__global__ void __launch_bounds__(256)
cvt_lw_kernel(const float* __restrict__ LW, _Float16* __restrict__ LWh) {
    const int o = blockIdx.x;
    for (int f = threadIdx.x; f < FP; f += 256)
        LWh[o * FP + f] = (f < 1072) ? (_Float16)LW[o * 1072 + f] : (_Float16)0.f;
}

__global__ void __launch_bounds__(256, 4)
pconv_linear_mfma(const float* __restrict__ inF,   // [2][60000][64]
                  const int*   __restrict__ inds,  // [2][60000][16]
                  const float* __restrict__ Wn,    // [2][60000][16][16]
                  const float* __restrict__ addF,  // [2][60000][16][3]
                  const _Float16* __restrict__ LWh,// [128][1088] f16 (d_ws)
                  const float* __restrict__ bias,  // [128]
                  float*       __restrict__ out)   // [2][60000][128]
{
    __shared__ __align__(16) _Float16 sP[16 * PSTR];

    const int t    = threadIdx.x;
    const int lane = t & 63;
    const int w    = t >> 6;        // wave 0..3
    const int q    = lane >> 4;     // quad 0..3
    const int ml   = lane & 15;
    const bool qlo = (q < 2);       // quads 0,1 carry the real K=16; 2,3 are zero-pad

    const int bid = blockIdx.x;
    const int b   = bid / NBLK;
    const int n0  = (bid - b * NBLK) * 16;

    const f32x4 z4 = {0.f, 0.f, 0.f, 0.f};

    // ================= Phase A: pconv via MFMA, one point per wave-step =================
    // D[c_off][m] = A[c_off][k] * B[k][m];  A[row=ml][k=q*8+j] = feat[k][c0+ml],
    // B[col=ml][k=q*8+j] = Wn[k][ml];  D: row c_off = q*4+r, col m = ml.
    for (int i = 0; i < 4; ++i) {
        const int p = w * 4 + i;
        const int base_nk = (b * NPTS + n0 + p) * 16;

        int rb[8];
        f16x8 bf = {0,0,0,0,0,0,0,0};
        if (qlo) {
            #pragma unroll
            for (int j = 0; j < 8; ++j)
                rb[j] = (b * NPTS + inds[base_nk + q * 8 + j]) * 64;
            #pragma unroll
            for (int j = 0; j < 8; ++j)
                bf[j] = (_Float16)Wn[(base_nk + q * 8 + j) * 16 + ml];
        }

        #pragma unroll
        for (int ct = 0; ct < 4; ++ct) {          // c-tiles 0..3: c = 0..63 from gather
            f16x8 af = {0,0,0,0,0,0,0,0};
            if (qlo) {
                const int c = ct * 16 + ml;
                #pragma unroll
                for (int j = 0; j < 8; ++j)
                    af[j] = (_Float16)inF[rb[j] + c];
            }
            f32x4 d = __builtin_amdgcn_mfma_f32_16x16x32_f16(af, bf, z4, 0, 0, 0);
            #pragma unroll
            for (int r = 0; r < 4; ++r)
                sP[p * PSTR + (ct * 16 + q * 4 + r) * 16 + ml] = (_Float16)d[r];
        }
        {   // c-tile 4: c = 64..66 from additional_features; row 67 = 0 -> pads f[1072,1088)
            f16x8 af = {0,0,0,0,0,0,0,0};
            if (qlo && ml < 3) {
                #pragma unroll
                for (int j = 0; j < 8; ++j)
                    af[j] = (_Float16)addF[(base_nk + q * 8 + j) * 3 + ml];
            }
            f32x4 d = __builtin_amdgcn_mfma_f32_16x16x32_f16(af, bf, z4, 0, 0, 0);
            if (q == 0) {       // rows c=64..67 only; c>=68 are zero and out of sP range
                #pragma unroll
                for (int r = 0; r < 4; ++r)
                    sP[p * PSTR + (64 + r) * 16 + ml] = (_Float16)d[r];
            }
        }
    }
    __syncthreads();

    // ================= Phase B: out[16 x 128] = sP @ LWh^T, MFMA over 34 K-chunks =======
    // Wave w owns o-tiles {w*32, w*32+16}. A[row=p=ml][k], B[col=o=ml][k], shared A-frag.
    const int o0 = w * 32;
    f32x4 acc0 = {0.f,0.f,0.f,0.f};
    f32x4 acc1 = {0.f,0.f,0.f,0.f};
    const _Float16* aP  = sP + ml * PSTR + q * 8;
    const _Float16* bP0 = LWh + (o0 + ml) * FP + q * 8;
    const _Float16* bP1 = bP0 + 16 * FP;

    #pragma unroll 2
    for (int ch = 0; ch < 34; ++ch) {
        f16x8 a  = *(const f16x8*)(aP  + ch * 32);   // ds_read_b128, bank-balanced
        f16x8 b0 = *(const f16x8*)(bP0 + ch * 32);   // global dwordx4, L2-resident
        f16x8 b1 = *(const f16x8*)(bP1 + ch * 32);
        acc0 = __builtin_amdgcn_mfma_f32_16x16x32_f16(a, b0, acc0, 0, 0, 0);
        acc1 = __builtin_amdgcn_mfma_f32_16x16x32_f16(a, b1, acc1, 0, 0, 0);
    }

    // ================= Epilogue: bias + store (rows p = q*4+r, cols o0+ml / o0+16+ml) ===
    const float bz0 = bias[o0 + ml];
    const float bz1 = bias[o0 + 16 + ml];
    float* obase = out + (b * NPTS + n0 + q * 4) * 128;
    #pragma unroll
    for (int r = 0; r < 4; ++r) {
        obase[r * 128 + o0 + ml]      = acc0[r] + bz0;
        obase[r * 128 + o0 + 16 + ml] = acc1[r] + bz1;
    }
}

extern "C" void kernel_launch(void* const* d_in, const int* in_sizes, int n_in,
                              void* d_out, int out_size, void* d_ws, size_t ws_size,
                              hipStream_t stream)
{
    const float* inF  = (const float*)d_in[0];
    const int*   inds = (const int*)  d_in[1];
    const float* Wn   = (const float*)d_in[2];
    const float* addF = (const float*)d_in[3];
    const float* LW   = (const float*)d_in[4];
    const float* bias = (const float*)d_in[5];
    float* out = (float*)d_out;
    _Float16* LWh = (_Float16*)d_ws;    // 278,528 B of scratch

    cvt_lw_kernel<<<dim3(128), dim3(256), 0, stream>>>(LW, LWh);
    pconv_linear_mfma<<<dim3(2 * NBLK), dim3(256), 0, stream>>>(
        inF, inds, Wn, addF, LWh, bias, out);
}

// Round 3
// 514.827 us; speedup vs baseline: 2.0396x; 1.0087x over previous
//
#include <hip/hip_runtime.h>
#include <hip/hip_bf16.h>

// PConvLinear: B=2, N=60000, K=16, C_in=64, C_add=3, C_mid=16.
// pconv[p][c][m] = sum_k feat[p][k][c] * Wn[p][k][m]   (c in 0..66)
// out[p][o]     = sum_f pconv_flat[p][f] * LW[o][f] + bias[o],  f = c*16+m, F=1072
#define NPTS  60000
#define NBLK  3750          // blocks per batch (16 points each)
#define FP    1088          // F padded to 34*32 for K-chunking
#define PSTR  1096          // sP row stride (f16): 548 dw, %32=4 -> 2-way (free)
#define KSTR  20            // sT row stride (f16): 40 B -> 8B-aligned b64 reads, 2-way banks

typedef _Float16 f16x8 __attribute__((ext_vector_type(8)));
typedef _Float16 f16x4 __attribute__((ext_vector_type(4)));
typedef float    f32x4 __attribute__((ext_vector_type(4)));

// ---- pre-kernel: linear_weight fp32 [128][1072] -> f16 [128][1088] in d_ws ----
__global__ void __launch_bounds__(256)
cvt_lw_kernel(const float* __restrict__ LW, _Float16* __restrict__ LWh) {
    const int o = blockIdx.x;
    for (int f = threadIdx.x; f < FP; f += 256)
        LWh[o * FP + f] = (f < 1072) ? (_Float16)LW[o * 1072 + f] : (_Float16)0.f;
}

__global__ void __launch_bounds__(256, 4)
pconv_linear_mfma(const float* __restrict__ inF,   // [2][60000][64]
                  const int*   __restrict__ inds,  // [2][60000][16]
                  const float* __restrict__ Wn,    // [2][60000][16][16]
                  const float* __restrict__ addF,  // [2][60000][16][3]
                  const _Float16* __restrict__ LWh,// [128][1088] f16 (d_ws)
                  const float* __restrict__ bias,  // [128]
                  float*       __restrict__ out)   // [2][60000][128]
{
    __shared__ __align__(16) _Float16 sP[16 * PSTR];       // pconv tile [p][f]
    __shared__ __align__(16) _Float16 sT[4][32 * KSTR];    // per-wave gather tile [c'][k]

    const int t    = threadIdx.x;
    const int lane = t & 63;
    const int w    = t >> 6;        // wave 0..3
    const int q    = lane >> 4;     // quad 0..3
    const int ml   = lane & 15;
    const bool qlo = (q < 2);       // quads 0,1 carry the real K=16; 2,3 zero-pad

    const int bid = blockIdx.x;
    const int b   = bid / NBLK;
    const int n0  = (bid - b * NBLK) * 16;

    const f32x4 z4 = {0.f, 0.f, 0.f, 0.f};

    // One coalesced load: lane l holds inds[point w*4 + (l>>4)][k = l&15]
    const int ind_lane = inds[(b * NPTS + n0 + w * 4) * 16 + lane];

    _Float16* T = &sT[w][0];
    const int k0  = (lane >> 3) * 2;   // even row pair this lane gathers
    const int seg = lane & 7;          // 4-float segment within the 32-c half

    // ================= Phase A: pconv via MFMA, coalesced gather through sT =============
    for (int i = 0; i < 4; ++i) {
        const int p = w * 4 + i;
        const int base_nk = (b * NPTS + n0 + p) * 16;

        // B-frag: Wn[k][ml], k = q*8+j (streaming loads, 64B-contig per quad)
        f16x8 bf = {0,0,0,0,0,0,0,0};
        if (qlo) {
            #pragma unroll
            for (int j = 0; j < 8; ++j)
                bf[j] = (_Float16)Wn[(base_nk + q * 8 + j) * 16 + ml];
        }
        // addF A-frag (c-tile 4): rows c=64..66
        f16x8 afA = {0,0,0,0,0,0,0,0};
        if (qlo && ml < 3) {
            #pragma unroll
            for (int j = 0; j < 8; ++j)
                afA[j] = (_Float16)addF[(base_nk + q * 8 + j) * 3 + ml];
        }

        #pragma unroll
        for (int ch = 0; ch < 2; ++ch) {      // two 32-channel halves of c=0..63
            const int idx0 = __shfl(ind_lane, i * 16 + k0,     64);
            const int idx1 = __shfl(ind_lane, i * 16 + k0 + 1, 64);
            const float4 v0 = *(const float4*)(inF + (b * NPTS + idx0) * 64 + ch * 32 + seg * 4);
            const float4 v1 = *(const float4*)(inF + (b * NPTS + idx1) * 64 + ch * 32 + seg * 4);

            // pack (k0, k0+1) f16 pairs -> conflict-free ds_write_b32 into T[c'][k]
            {
                const float a0[4] = {v0.x, v0.y, v0.z, v0.w};
                const float a1[4] = {v1.x, v1.y, v1.z, v1.w};
                #pragma unroll
                for (int cc = 0; cc < 4; ++cc) {
                    union { _Float16 h[2]; unsigned u; } pk;
                    pk.h[0] = (_Float16)a0[cc];
                    pk.h[1] = (_Float16)a1[cc];
                    *(unsigned*)&T[(seg * 4 + cc) * KSTR + k0] = pk.u;
                }
            }

            // consume: 2 c-tiles per half; A[row=ml][k=q*8+j] = T[c'=h*16+ml][k]
            #pragma unroll
            for (int h = 0; h < 2; ++h) {
                f16x8 a = {0,0,0,0,0,0,0,0};
                if (qlo) {
                    const _Float16* ap = T + (h * 16 + ml) * KSTR + q * 8;
                    const f16x4 alo = *(const f16x4*)ap;        // ds_read_b64 (8B aligned)
                    const f16x4 ahi = *(const f16x4*)(ap + 4);
                    a[0]=alo[0]; a[1]=alo[1]; a[2]=alo[2]; a[3]=alo[3];
                    a[4]=ahi[0]; a[5]=ahi[1]; a[6]=ahi[2]; a[7]=ahi[3];
                }
                const f32x4 d = __builtin_amdgcn_mfma_f32_16x16x32_f16(a, bf, z4, 0, 0, 0);
                const int ct = ch * 2 + h;
                #pragma unroll
                for (int r = 0; r < 4; ++r)
                    sP[p * PSTR + (ct * 16 + q * 4 + r) * 16 + ml] = (_Float16)d[r];
            }
        }

        // c-tile 4: c=64..66 from addF; D row 3 zeros -> f[1072,1088) pad
        {
            const f32x4 d = __builtin_amdgcn_mfma_f32_16x16x32_f16(afA, bf, z4, 0, 0, 0);
            if (q == 0) {
                #pragma unroll
                for (int r = 0; r < 4; ++r)
                    sP[p * PSTR + (64 + r) * 16 + ml] = (_Float16)d[r];
            }
        }
    }
    __syncthreads();

    // ================= Phase B: out[16 x 128] = sP @ LWh^T, MFMA over 34 K-chunks =======
    // Wave w owns o-tiles {w*32, w*32+16}. A[row=p=ml][k], B[col=o=ml][k], shared A-frag.
    const int o0 = w * 32;
    f32x4 acc0 = {0.f,0.f,0.f,0.f};
    f32x4 acc1 = {0.f,0.f,0.f,0.f};
    const _Float16* aP  = sP + ml * PSTR + q * 8;
    const _Float16* bP0 = LWh + (o0 + ml) * FP + q * 8;
    const _Float16* bP1 = bP0 + 16 * FP;

    #pragma unroll 2
    for (int ch = 0; ch < 34; ++ch) {
        f16x8 a  = *(const f16x8*)(aP  + ch * 32);   // ds_read_b128, bank-balanced
        f16x8 b0 = *(const f16x8*)(bP0 + ch * 32);   // global dwordx4, L2-resident
        f16x8 b1 = *(const f16x8*)(bP1 + ch * 32);
        acc0 = __builtin_amdgcn_mfma_f32_16x16x32_f16(a, b0, acc0, 0, 0, 0);
        acc1 = __builtin_amdgcn_mfma_f32_16x16x32_f16(a, b1, acc1, 0, 0, 0);
    }

    // ================= Epilogue: bias + store (rows p = q*4+r, cols o0+ml / o0+16+ml) ===
    const float bz0 = bias[o0 + ml];
    const float bz1 = bias[o0 + 16 + ml];
    float* obase = out + (b * NPTS + n0 + q * 4) * 128;
    #pragma unroll
    for (int r = 0; r < 4; ++r) {
        obase[r * 128 + o0 + ml]      = acc0[r] + bz0;
        obase[r * 128 + o0 + 16 + ml] = acc1[r] + bz1;
    }
}

extern "C" void kernel_launch(void* const* d_in, const int* in_sizes, int n_in,
                              void* d_out, int out_size, void* d_ws, size_t ws_size,
                              hipStream_t stream)
{
    const float* inF  = (const float*)d_in[0];
    const int*   inds = (const int*)  d_in[1];
    const float* Wn   = (const float*)d_in[2];
    const float* addF = (const float*)d_in[3];
    const float* LW   = (const float*)d_in[4];
    const float* bias = (const float*)d_in[5];
    float* out = (float*)d_out;
    _Float16* LWh = (_Float16*)d_ws;    // 278,528 B of scratch

    cvt_lw_kernel<<<dim3(128), dim3(256), 0, stream>>>(LW, LWh);
    pconv_linear_mfma<<<dim3(2 * NBLK), dim3(256), 0, stream>>>(
        inF, inds, Wn, addF, LWh, bias, out);
}